// Round 1
// baseline (248.268 us; speedup 1.0000x reference)
//
#include <hip/hip_runtime.h>

typedef unsigned short u16;
typedef unsigned int u32;

#define C_DIM 192
#define N_TOK 16384
#define M_LEN 256
#define HD 32
#define NH 6

#define AF_STRIDE 3080   // u16 per-token-tile A-frag region (6*512 + 8 skew)

typedef __attribute__((ext_vector_type(8))) short short8v;
typedef __attribute__((ext_vector_type(4))) float float4v;

// Hardware bf16 convert: 2 f32 -> packed 2x bf16 (RNE), 1 instruction.
__device__ __forceinline__ u32 cvt_pk_bf16(float lo, float hi) {
    u32 r;
    asm("v_cvt_pk_bf16_f32 %0, %1, %2" : "=v"(r) : "v"(lo), "v"(hi));
    return r;
}
__device__ __forceinline__ u16 f2bf_hw(float f) {
    return (u16)cvt_pk_bf16(f, f);
}

// ---------------- Kernel W: Wq -> fragment-ordered bf16 ----------------
// 72 frags (wv 0..3, kt 0..5, jj 0..2), each 64 lanes x 8 u16.
// grid: 18 blocks x 256 threads.
__global__ __launch_bounds__(256) void wq_prep(
    const float* __restrict__ Wq, u16* __restrict__ WqF)
{
    int gt = blockIdx.x * 256 + threadIdx.x;
    int f = gt >> 6, lane = gt & 63;
    int q8 = lane >> 4, ln = lane & 15;
    int wv = f / 18, r = f % 18;
    int kt = r / 3, jj = r % 3;
    const float* w0 = Wq + (kt * 32 + q8 * 8) * C_DIM + (wv * 3 + jj) * 16 + ln;
    union { u32 w[4]; short8v v; } out;
#pragma unroll
    for (int j = 0; j < 4; ++j)
        out.w[j] = cvt_pk_bf16(w0[(2 * j) * C_DIM], w0[(2 * j + 1) * C_DIM]);
    *(short8v*)&WqF[f * 512 + lane * 8] = out.v;
}

// ---------------- Kernel A: LN1 + Q projection via MFMA ----------------
// grid: 1024 blocks, 256 threads. Block: 64 tokens x 192 outputs.
__global__ __launch_bounds__(256) void ln1_q_mfma(
    const float* __restrict__ x, const float* __restrict__ g,
    const float* __restrict__ beta, const u16* __restrict__ WqF,
    u16* __restrict__ q)
{
    __shared__ u16 Af[4 * AF_STRIDE];      // A-frags, 4 token-tiles
    __shared__ u16 Tq[64 * 200];           // [tok][c] transpose, stride 200
    __shared__ float part[64][4][2];
    __shared__ float mu_s[64], rs_s[64];
    int b = blockIdx.x >> 8;
    int n0 = (blockIdx.x & 255) * 64;
    int t = threadIdx.x;
    int wv = t >> 6, lane = t & 63;

    // ---- phase 1: load x slice into regs (wave w: c in [48w,48w+48)) ----
    float xv[48];
    {
        const float* xb = x + (((size_t)(b * C_DIM + wv * 48)) << 14) + n0 + lane;
        float s1 = 0.f, s2 = 0.f;
#pragma unroll
        for (int i = 0; i < 48; ++i) {
            float f = xb[(size_t)i << 14];
            xv[i] = f; s1 += f; s2 += f * f;
        }
        part[lane][wv][0] = s1; part[lane][wv][1] = s2;
    }
    __syncthreads();
    if (t < 64) {
        float a  = part[t][0][0] + part[t][1][0] + part[t][2][0] + part[t][3][0];
        float c2 = part[t][0][1] + part[t][1][1] + part[t][2][1] + part[t][3][1];
        float mu = a * (1.f / C_DIM);
        mu_s[t] = mu;
        rs_s[t] = rsqrtf(c2 * (1.f / C_DIM) - mu * mu + 1e-5f);
    }
    __syncthreads();

    // ---- phase 2: normalize, pack bf16 pairs into A-frag LDS ----
    {
        float mu = mu_s[lane], rs = rs_s[lane];
        int mt2 = lane >> 4, ln2 = lane & 15;
        u32* A32 = (u32*)Af;
#pragma unroll
        for (int i = 0; i < 48; i += 2) {
            int c = wv * 48 + i;
            float f0 = (xv[i]     - mu) * rs * g[c]     + beta[c];
            float f1 = (xv[i + 1] - mu) * rs * g[c + 1] + beta[c + 1];
            int kt = c >> 5, k8 = (c & 31) >> 3, j = c & 7;
            A32[(mt2 * AF_STRIDE + kt * 512 + k8 * 128 + ln2 * 8 + j) >> 1] =
                cvt_pk_bf16(f0, f1);
        }
    }
    __syncthreads();

    // ---- phase 3: Wq B-frags from prepped buffer (coalesced 16B loads) ----
    int q8 = lane >> 4, ln = lane & 15;
    short8v Bf[18];
#pragma unroll
    for (int i = 0; i < 18; ++i)
        Bf[i] = *(const short8v*)&WqF[(wv * 18 + i) * 512 + lane * 8];

    // ---- phase 4: MFMA + write C to transpose LDS ----
#pragma unroll
    for (int mt = 0; mt < 4; ++mt) {
        float4v acc[3] = {{0.f,0.f,0.f,0.f},{0.f,0.f,0.f,0.f},{0.f,0.f,0.f,0.f}};
#pragma unroll
        for (int kt = 0; kt < 6; ++kt) {
            short8v a = *(const short8v*)&Af[mt * AF_STRIDE + kt * 512 + lane * 8];
#pragma unroll
            for (int jj = 0; jj < 3; ++jj)
                acc[jj] = __builtin_amdgcn_mfma_f32_16x16x32_bf16(a, Bf[kt * 3 + jj], acc[jj], 0, 0, 0);
        }
#pragma unroll
        for (int jj = 0; jj < 3; ++jj)
#pragma unroll
            for (int r = 0; r < 4; ++r)
                Tq[(mt * 16 + q8 * 4 + r) * 200 + (wv * 3 + jj) * 16 + ln] = f2bf_hw(acc[jj][r]);
    }
    __syncthreads();

    // ---- phase 5: vectorized q store (48 u16 = 6 uint4 per chunk) ----
    {
        int tok = t >> 2, pp = t & 3;
        const uint4* src = (const uint4*)&Tq[tok * 200 + pp * 48];
        uint4* dst = (uint4*)(q + ((size_t)(b * N_TOK + n0 + tok)) * C_DIM + pp * 48);
#pragma unroll
        for (int i = 0; i < 6; ++i) dst[i] = src[i];
    }
}

// ---------------- Kernel B: LN2 + KV projection (fp32 k/v) ----------------
__global__ __launch_bounds__(192) void ln2_kv_kernel(
    const float* __restrict__ prior, const float* __restrict__ g,
    const float* __restrict__ beta, const float* __restrict__ Wkv,
    float* __restrict__ k, float* __restrict__ v)
{
    __shared__ float pr[C_DIM];
    __shared__ float red[3][2];
    int row = blockIdx.x;
    int tid = threadIdx.x;
    int wv = tid >> 6;
    float val = prior[row * C_DIM + tid];
    // wave-parallel stats
    float s1 = val, s2 = val * val;
#pragma unroll
    for (int m = 1; m < 64; m <<= 1) {
        s1 += __shfl_xor(s1, m);
        s2 += __shfl_xor(s2, m);
    }
    if ((tid & 63) == 0) { red[wv][0] = s1; red[wv][1] = s2; }
    __syncthreads();
    float a  = red[0][0] + red[1][0] + red[2][0];
    float c2 = red[0][1] + red[1][1] + red[2][1];
    float mu = a * (1.f / C_DIM);
    float rs = rsqrtf(c2 * (1.f / C_DIM) - mu * mu + 1e-5f);
    pr[tid] = (val - mu) * rs * g[tid] + beta[tid];
    __syncthreads();
    float ka = 0.f, va = 0.f;
    for (int c = 0; c < C_DIM; ++c) {
        float p = pr[c];
        ka += p * Wkv[c * 384 + tid];
        va += p * Wkv[c * 384 + 192 + tid];
    }
    k[row * C_DIM + tid] = ka;
    v[row * C_DIM + tid] = va;
}

// ---------------- Kernel KV: pack K/V into fragment-ordered bf16 ----------
// grid: 24 blocks (b*NH+h), 256 threads. Runs ONCE per (b,h) tile.
__global__ __launch_bounds__(256) void kv_prep(
    const float* __restrict__ kg, const float* __restrict__ vg,
    u16* __restrict__ KfG, u16* __restrict__ VfG)
{
    int bh = blockIdx.x;
    int h = bh % NH, b = bh / NH;
    int tid = threadIdx.x;
    const float scale = 0.17677669529663687f;
    u16* Kd = KfG + bh * 8192;
    u16* Vd = VfG + bh * 8192;
    for (int i = tid; i < 8192; i += 256) {
        int key = i >> 5, dim = i & 31;
        int gidx = (b * M_LEN + key) * C_DIM + h * HD + dim;
        {
            float f = kg[gidx] * scale;
            int kt = key >> 4, r = key & 15, qd = dim >> 3, j = dim & 7;
            Kd[kt * 512 + (qd * 16 + r) * 8 + j] = f2bf_hw(f);
        }
        {
            float f = vg[gidx];
            int kt = key >> 4, r = key & 15;
            int qd = r >> 2, reg = r & 3;
            int P = kt >> 1;
            int j = reg + 4 * (kt & 1);
            int dh = dim >> 4, n = dim & 15;
            Vd[(P * 2 + dh) * 512 + (qd * 16 + n) * 8 + j] = f2bf_hw(f);
        }
    }
}

// ---------------- Kernel C: MFMA attention v4 ----------------
// grid: B*NH*64 = 1536 blocks, 256 threads. Block: 256 tokens (4 reps/wave).
// v4: hw cvt_pk bf16 pack, exp2+fma softmax, v_rcp, q prefetch 1 rep ahead.
__global__ __launch_bounds__(256) void attn_mfma_kernel(
    const u16* __restrict__ q, const u16* __restrict__ KfG,
    const u16* __restrict__ VfG, u16* __restrict__ att)
{
    __shared__ u16 sh[16384];   // [0,8192): Kf, [8192,16384): Vf
    int tb = blockIdx.x & 63;
    int bh = blockIdx.x >> 6;
    int h = bh % NH, b = bh / NH;
    int tid = threadIdx.x;
    int wave = tid >> 6, lane = tid & 63;
    int quad = lane >> 4, ln = lane & 15;

    // issue rep-0 q load before staging so it overlaps the barrier wait
    const u16* qbase = q + ((size_t)(b * N_TOK + tb * 256 + wave * 16 + ln)) * C_DIM
                         + h * HD + quad * 8;
    short8v qnext = *(const short8v*)qbase;

    {
        const uint4* Ks = (const uint4*)(KfG + bh * 8192);
        const uint4* Vs = (const uint4*)(VfG + bh * 8192);
        uint4* d = (uint4*)sh;
#pragma unroll
        for (int i = tid; i < 2048; i += 256)
            d[i] = (i < 1024) ? Ks[i] : Vs[i - 1024];
    }
    __syncthreads();

    const u16* Kf = sh;
    const u16* Vf = sh + 8192;
    const float LOG2E = 1.4426950408889634f;

    for (int rep = 0; rep < 4; ++rep) {
        short8v qf = qnext;
        int nrep = rep < 3 ? rep + 1 : 3;
        qnext = *(const short8v*)(qbase + (size_t)nrep * 64 * C_DIM);

        float4v s[16];
#pragma unroll
        for (int kt = 0; kt < 16; ++kt) {
            short8v kf = *(const short8v*)&Kf[kt * 512 + lane * 8];
            float4v z = {0.f, 0.f, 0.f, 0.f};
            s[kt] = __builtin_amdgcn_mfma_f32_16x16x32_bf16(kf, qf, z, 0, 0, 0);
        }

        // max over the 64 local scores (max3-friendly tree), then cross-quad
        float mx = fmaxf(fmaxf(s[0][0], s[0][1]), fmaxf(s[0][2], s[0][3]));
#pragma unroll
        for (int kt = 1; kt < 16; ++kt)
            mx = fmaxf(fmaxf(mx, s[kt][0]),
                       fmaxf(s[kt][1], fmaxf(s[kt][2], s[kt][3])));
        mx = fmaxf(mx, __shfl_xor(mx, 16));
        mx = fmaxf(mx, __shfl_xor(mx, 32));

        // p = exp(s - mx) = exp2(fma(s, log2e, -mx*log2e)) : 2 VALU/elem
        float nm = -mx * LOG2E;
        float l = 0.f;
#pragma unroll
        for (int kt = 0; kt < 16; ++kt) {
#pragma unroll
            for (int r = 0; r < 4; ++r) {
                float p = __builtin_amdgcn_exp2f(fmaf(s[kt][r], LOG2E, nm));
                s[kt][r] = p;
                l += p;
            }
        }
        l += __shfl_xor(l, 16);
        l += __shfl_xor(l, 32);
        float inv = __builtin_amdgcn_rcpf(l);   // feeds bf16, approx rcp is fine

        float4v o0 = {0.f, 0.f, 0.f, 0.f}, o1 = {0.f, 0.f, 0.f, 0.f};
#pragma unroll
        for (int P = 0; P < 8; ++P) {
            union { u32 w[4]; short8v v; } pf;
            pf.w[0] = cvt_pk_bf16(s[2 * P][0],     s[2 * P][1]);
            pf.w[1] = cvt_pk_bf16(s[2 * P][2],     s[2 * P][3]);
            pf.w[2] = cvt_pk_bf16(s[2 * P + 1][0], s[2 * P + 1][1]);
            pf.w[3] = cvt_pk_bf16(s[2 * P + 1][2], s[2 * P + 1][3]);
            short8v v0 = *(const short8v*)&Vf[(P * 2 + 0) * 512 + lane * 8];
            short8v v1 = *(const short8v*)&Vf[(P * 2 + 1) * 512 + lane * 8];
            o0 = __builtin_amdgcn_mfma_f32_16x16x32_bf16(pf.v, v0, o0, 0, 0, 0);
            o1 = __builtin_amdgcn_mfma_f32_16x16x32_bf16(pf.v, v1, o1, 0, 0, 0);
        }

        int token0 = tb * 256 + rep * 64 + wave * 16;
#pragma unroll
        for (int r = 0; r < 4; ++r) {
            float invr = __shfl(inv, quad * 4 + r);
            u16* row = att + ((size_t)(b * N_TOK + token0 + quad * 4 + r)) * C_DIM + h * HD;
            row[ln]      = f2bf_hw(o0[r] * invr);
            row[16 + ln] = f2bf_hw(o1[r] * invr);
        }
    }
}

// ---------------- Kernel D: out projection + residual via MFMA --------------
__global__ __launch_bounds__(256) void proj_res_mfma(
    const u16* __restrict__ att, const float* __restrict__ Wp,
    const float* __restrict__ bp, const float* __restrict__ x,
    float* __restrict__ y)
{
    __shared__ float Tf[C_DIM * 68];   // [c][tok] fp32 transpose, stride 68
    int b = blockIdx.x >> 8;
    int n0 = (blockIdx.x & 255) * 64;
    int t = threadIdx.x;
    int wv = t >> 6, lane = t & 63;
    int q8 = lane >> 4, ln = lane & 15;

    short8v Bf[18];
#pragma unroll
    for (int kt = 0; kt < 6; ++kt) {
#pragma unroll
        for (int jj = 0; jj < 3; ++jj) {
            const float* w0 = Wp + (kt * 32 + q8 * 8) * C_DIM + (wv * 3 + jj) * 16 + ln;
            union { u32 w[4]; short8v v; } f;
#pragma unroll
            for (int wj = 0; wj < 4; ++wj)
                f.w[wj] = cvt_pk_bf16(w0[(2 * wj) * C_DIM], w0[(2 * wj + 1) * C_DIM]);
            Bf[kt * 3 + jj] = f.v;
        }
    }

#pragma unroll
    for (int mt = 0; mt < 4; ++mt) {
        const u16* ab = att + ((size_t)(b * N_TOK + n0 + mt * 16 + ln)) * C_DIM + q8 * 8;
        float4v acc[3] = {{0.f,0.f,0.f,0.f},{0.f,0.f,0.f,0.f},{0.f,0.f,0.f,0.f}};
#pragma unroll
        for (int kt = 0; kt < 6; ++kt) {
            short8v a = *(const short8v*)(ab + kt * 32);
#pragma unroll
            for (int jj = 0; jj < 3; ++jj)
                acc[jj] = __builtin_amdgcn_mfma_f32_16x16x32_bf16(a, Bf[kt * 3 + jj], acc[jj], 0, 0, 0);
        }
#pragma unroll
        for (int jj = 0; jj < 3; ++jj)
#pragma unroll
            for (int r = 0; r < 4; ++r)
                Tf[((wv * 3 + jj) * 16 + ln) * 68 + mt * 16 + q8 * 4 + r] = acc[jj][r];
    }
    __syncthreads();

    if (t < C_DIM) {
        int c = t;
        float bias = bp[c];
        const float4* xr = (const float4*)(x + (((size_t)(b * C_DIM + c)) << 14) + n0);
        float4*       yr = (float4*)(y + (((size_t)(b * C_DIM + c)) << 14) + n0);
        const float4* tr = (const float4*)&Tf[c * 68];
#pragma unroll
        for (int i = 0; i < 16; ++i) {
            float4 u = xr[i], a = tr[i];
            float4 w;
            w.x = a.x + bias + u.x;
            w.y = a.y + bias + u.y;
            w.z = a.z + bias + u.z;
            w.w = a.w + bias + u.w;
            yr[i] = w;
        }
    }
}

extern "C" void kernel_launch(void* const* d_in, const int* in_sizes, int n_in,
                              void* d_out, int out_size, void* d_ws, size_t ws_size,
                              hipStream_t stream) {
    const float* x     = (const float*)d_in[0];
    const float* prior = (const float*)d_in[1];
    const float* ln1_g = (const float*)d_in[2];
    const float* ln1_b = (const float*)d_in[3];
    const float* ln2_g = (const float*)d_in[4];
    const float* ln2_b = (const float*)d_in[5];
    const float* Wq    = (const float*)d_in[6];
    const float* Wkv   = (const float*)d_in[7];
    const float* Wp    = (const float*)d_in[8];
    const float* bp    = (const float*)d_in[9];

    // d_out (50.3 MB fp32) multiplexed (y overwrites everything at the end):
    //   [0,        25165824): q bf16
    //   [25165824, 25952256): k fp32
    //   [25952256, 26738688): v fp32
    //   [26738688, 26812416): WqF  bf16 fragment-ordered (72 frags x 1KB)
    //   [26812416, 27205632): KfG  bf16 fragments (24 x 16KB)
    //   [27205632, 27598848): VfG  bf16 fragments (24 x 16KB)
    // d_ws: att bf16 (25.2 MB) only.
    char* outc = (char*)d_out;
    u16*   q    = (u16*)outc;
    float* kbuf = (float*)(outc + 25165824);
    float* vbuf = (float*)(outc + 25952256);
    u16*   WqF  = (u16*)(outc + 26738688);
    u16*   KfG  = (u16*)(outc + 26812416);
    u16*   VfG  = (u16*)(outc + 27205632);
    u16*   att  = (u16*)d_ws;
    float* y    = (float*)d_out;

    wq_prep<<<18, 256, 0, stream>>>(Wq, WqF);
    ln1_q_mfma<<<1024, 256, 0, stream>>>(x, ln1_g, ln1_b, WqF, q);
    ln2_kv_kernel<<<1024, 192, 0, stream>>>(prior, ln2_g, ln2_b, Wkv, kbuf, vbuf);
    kv_prep<<<24, 256, 0, stream>>>(kbuf, vbuf, KfG, VfG);
    attn_mfma_kernel<<<1536, 256, 0, stream>>>(q, KfG, VfG, att);
    proj_res_mfma<<<1024, 256, 0, stream>>>(att, Wp, bp, x, y);
}

// Round 2
// 204.483 us; speedup vs baseline: 1.2141x; 1.2141x over previous
//
#include <hip/hip_runtime.h>

typedef unsigned short u16;
typedef unsigned int u32;

#define C_DIM 192
#define N_TOK 16384
#define M_LEN 256
#define HD 32
#define NH 6

#define AF_STRIDE 3080   // u16 per-token-tile A-frag region (6*512 + 8 skew)

typedef __attribute__((ext_vector_type(8))) short short8v;
typedef __attribute__((ext_vector_type(4))) float float4v;

// Hardware bf16 convert: 2 f32 -> packed 2x bf16 (RNE), 1 instruction.
__device__ __forceinline__ u32 cvt_pk_bf16(float lo, float hi) {
    u32 r;
    asm("v_cvt_pk_bf16_f32 %0, %1, %2" : "=v"(r) : "v"(lo), "v"(hi));
    return r;
}
__device__ __forceinline__ u16 f2bf_hw(float f) {
    return (u16)cvt_pk_bf16(f, f);
}

// ---------------- Kernel W: 192x192 weight -> fragment-ordered bf16 --------
// 72 frags (wv 0..3, kt 0..5, jj 0..2), each 64 lanes x 8 u16.
// grid: 18 blocks x 256 threads. Used for BOTH Wq and Wp (same shape).
__global__ __launch_bounds__(256) void wq_prep(
    const float* __restrict__ Wq, u16* __restrict__ WqF)
{
    int gt = blockIdx.x * 256 + threadIdx.x;
    int f = gt >> 6, lane = gt & 63;
    int q8 = lane >> 4, ln = lane & 15;
    int wv = f / 18, r = f % 18;
    int kt = r / 3, jj = r % 3;
    const float* w0 = Wq + (kt * 32 + q8 * 8) * C_DIM + (wv * 3 + jj) * 16 + ln;
    union { u32 w[4]; short8v v; } out;
#pragma unroll
    for (int j = 0; j < 4; ++j)
        out.w[j] = cvt_pk_bf16(w0[(2 * j) * C_DIM], w0[(2 * j + 1) * C_DIM]);
    *(short8v*)&WqF[f * 512 + lane * 8] = out.v;
}

// ---------------- Kernel A: LN1 + Q projection via MFMA ----------------
// grid: 1024 blocks, 256 threads. Block: 64 tokens x 192 outputs.
__global__ __launch_bounds__(256) void ln1_q_mfma(
    const float* __restrict__ x, const float* __restrict__ g,
    const float* __restrict__ beta, const u16* __restrict__ WqF,
    u16* __restrict__ q)
{
    __shared__ u16 Af[4 * AF_STRIDE];      // A-frags, 4 token-tiles
    __shared__ u16 Tq[64 * 200];           // [tok][c] transpose, stride 200
    __shared__ float part[64][4][2];
    __shared__ float mu_s[64], rs_s[64];
    int b = blockIdx.x >> 8;
    int n0 = (blockIdx.x & 255) * 64;
    int t = threadIdx.x;
    int wv = t >> 6, lane = t & 63;

    // ---- phase 1: load x slice into regs (wave w: c in [48w,48w+48)) ----
    float xv[48];
    {
        const float* xb = x + (((size_t)(b * C_DIM + wv * 48)) << 14) + n0 + lane;
        float s1 = 0.f, s2 = 0.f;
#pragma unroll
        for (int i = 0; i < 48; ++i) {
            float f = xb[(size_t)i << 14];
            xv[i] = f; s1 += f; s2 += f * f;
        }
        part[lane][wv][0] = s1; part[lane][wv][1] = s2;
    }
    __syncthreads();
    if (t < 64) {
        float a  = part[t][0][0] + part[t][1][0] + part[t][2][0] + part[t][3][0];
        float c2 = part[t][0][1] + part[t][1][1] + part[t][2][1] + part[t][3][1];
        float mu = a * (1.f / C_DIM);
        mu_s[t] = mu;
        rs_s[t] = rsqrtf(c2 * (1.f / C_DIM) - mu * mu + 1e-5f);
    }
    __syncthreads();

    // ---- phase 2: normalize, pack bf16 pairs into A-frag LDS ----
    {
        float mu = mu_s[lane], rs = rs_s[lane];
        int mt2 = lane >> 4, ln2 = lane & 15;
        u32* A32 = (u32*)Af;
#pragma unroll
        for (int i = 0; i < 48; i += 2) {
            int c = wv * 48 + i;
            float f0 = (xv[i]     - mu) * rs * g[c]     + beta[c];
            float f1 = (xv[i + 1] - mu) * rs * g[c + 1] + beta[c + 1];
            int kt = c >> 5, k8 = (c & 31) >> 3, j = c & 7;
            A32[(mt2 * AF_STRIDE + kt * 512 + k8 * 128 + ln2 * 8 + j) >> 1] =
                cvt_pk_bf16(f0, f1);
        }
    }
    __syncthreads();

    // ---- phase 3: Wq B-frags from prepped buffer (coalesced 16B loads) ----
    int q8 = lane >> 4, ln = lane & 15;
    short8v Bf[18];
#pragma unroll
    for (int i = 0; i < 18; ++i)
        Bf[i] = *(const short8v*)&WqF[(wv * 18 + i) * 512 + lane * 8];

    // ---- phase 4: MFMA + write C to transpose LDS ----
#pragma unroll
    for (int mt = 0; mt < 4; ++mt) {
        float4v acc[3] = {{0.f,0.f,0.f,0.f},{0.f,0.f,0.f,0.f},{0.f,0.f,0.f,0.f}};
#pragma unroll
        for (int kt = 0; kt < 6; ++kt) {
            short8v a = *(const short8v*)&Af[mt * AF_STRIDE + kt * 512 + lane * 8];
#pragma unroll
            for (int jj = 0; jj < 3; ++jj)
                acc[jj] = __builtin_amdgcn_mfma_f32_16x16x32_bf16(a, Bf[kt * 3 + jj], acc[jj], 0, 0, 0);
        }
#pragma unroll
        for (int jj = 0; jj < 3; ++jj)
#pragma unroll
            for (int r = 0; r < 4; ++r)
                Tq[(mt * 16 + q8 * 4 + r) * 200 + (wv * 3 + jj) * 16 + ln] = f2bf_hw(acc[jj][r]);
    }
    __syncthreads();

    // ---- phase 5: vectorized q store (48 u16 = 6 uint4 per chunk) ----
    {
        int tok = t >> 2, pp = t & 3;
        const uint4* src = (const uint4*)&Tq[tok * 200 + pp * 48];
        uint4* dst = (uint4*)(q + ((size_t)(b * N_TOK + n0 + tok)) * C_DIM + pp * 48);
#pragma unroll
        for (int i = 0; i < 6; ++i) dst[i] = src[i];
    }
}

// ---------------- Kernel B: LN2 + KV projection (fp32 k/v) ----------------
__global__ __launch_bounds__(192) void ln2_kv_kernel(
    const float* __restrict__ prior, const float* __restrict__ g,
    const float* __restrict__ beta, const float* __restrict__ Wkv,
    float* __restrict__ k, float* __restrict__ v)
{
    __shared__ float pr[C_DIM];
    __shared__ float red[3][2];
    int row = blockIdx.x;
    int tid = threadIdx.x;
    int wv = tid >> 6;
    float val = prior[row * C_DIM + tid];
    // wave-parallel stats
    float s1 = val, s2 = val * val;
#pragma unroll
    for (int m = 1; m < 64; m <<= 1) {
        s1 += __shfl_xor(s1, m);
        s2 += __shfl_xor(s2, m);
    }
    if ((tid & 63) == 0) { red[wv][0] = s1; red[wv][1] = s2; }
    __syncthreads();
    float a  = red[0][0] + red[1][0] + red[2][0];
    float c2 = red[0][1] + red[1][1] + red[2][1];
    float mu = a * (1.f / C_DIM);
    float rs = rsqrtf(c2 * (1.f / C_DIM) - mu * mu + 1e-5f);
    pr[tid] = (val - mu) * rs * g[tid] + beta[tid];
    __syncthreads();
    float ka = 0.f, va = 0.f;
    for (int c = 0; c < C_DIM; ++c) {
        float p = pr[c];
        ka += p * Wkv[c * 384 + tid];
        va += p * Wkv[c * 384 + 192 + tid];
    }
    k[row * C_DIM + tid] = ka;
    v[row * C_DIM + tid] = va;
}

// ---------------- Kernel KV: pack K/V into fragment-ordered bf16 ----------
// grid: 24 blocks (b*NH+h), 256 threads. Runs ONCE per (b,h) tile.
__global__ __launch_bounds__(256) void kv_prep(
    const float* __restrict__ kg, const float* __restrict__ vg,
    u16* __restrict__ KfG, u16* __restrict__ VfG)
{
    int bh = blockIdx.x;
    int h = bh % NH, b = bh / NH;
    int tid = threadIdx.x;
    const float scale = 0.17677669529663687f;
    u16* Kd = KfG + bh * 8192;
    u16* Vd = VfG + bh * 8192;
    for (int i = tid; i < 8192; i += 256) {
        int key = i >> 5, dim = i & 31;
        int gidx = (b * M_LEN + key) * C_DIM + h * HD + dim;
        {
            float f = kg[gidx] * scale;
            int kt = key >> 4, r = key & 15, qd = dim >> 3, j = dim & 7;
            Kd[kt * 512 + (qd * 16 + r) * 8 + j] = f2bf_hw(f);
        }
        {
            float f = vg[gidx];
            int kt = key >> 4, r = key & 15;
            int qd = r >> 2, reg = r & 3;
            int P = kt >> 1;
            int j = reg + 4 * (kt & 1);
            int dh = dim >> 4, n = dim & 15;
            Vd[(P * 2 + dh) * 512 + (qd * 16 + n) * 8 + j] = f2bf_hw(f);
        }
    }
}

// ---------------- Kernel C: MFMA attention v4 ----------------
// grid: B*NH*64 = 1536 blocks, 256 threads. Block: 256 tokens (4 reps/wave).
__global__ __launch_bounds__(256) void attn_mfma_kernel(
    const u16* __restrict__ q, const u16* __restrict__ KfG,
    const u16* __restrict__ VfG, u16* __restrict__ att)
{
    __shared__ u16 sh[16384];   // [0,8192): Kf, [8192,16384): Vf
    int tb = blockIdx.x & 63;
    int bh = blockIdx.x >> 6;
    int h = bh % NH, b = bh / NH;
    int tid = threadIdx.x;
    int wave = tid >> 6, lane = tid & 63;
    int quad = lane >> 4, ln = lane & 15;

    // issue rep-0 q load before staging so it overlaps the barrier wait
    const u16* qbase = q + ((size_t)(b * N_TOK + tb * 256 + wave * 16 + ln)) * C_DIM
                         + h * HD + quad * 8;
    short8v qnext = *(const short8v*)qbase;

    {
        const uint4* Ks = (const uint4*)(KfG + bh * 8192);
        const uint4* Vs = (const uint4*)(VfG + bh * 8192);
        uint4* d = (uint4*)sh;
#pragma unroll
        for (int i = tid; i < 2048; i += 256)
            d[i] = (i < 1024) ? Ks[i] : Vs[i - 1024];
    }
    __syncthreads();

    const u16* Kf = sh;
    const u16* Vf = sh + 8192;
    const float LOG2E = 1.4426950408889634f;

    for (int rep = 0; rep < 4; ++rep) {
        short8v qf = qnext;
        int nrep = rep < 3 ? rep + 1 : 3;
        qnext = *(const short8v*)(qbase + (size_t)nrep * 64 * C_DIM);

        float4v s[16];
#pragma unroll
        for (int kt = 0; kt < 16; ++kt) {
            short8v kf = *(const short8v*)&Kf[kt * 512 + lane * 8];
            float4v z = {0.f, 0.f, 0.f, 0.f};
            s[kt] = __builtin_amdgcn_mfma_f32_16x16x32_bf16(kf, qf, z, 0, 0, 0);
        }

        // max over the 64 local scores (max3-friendly tree), then cross-quad
        float mx = fmaxf(fmaxf(s[0][0], s[0][1]), fmaxf(s[0][2], s[0][3]));
#pragma unroll
        for (int kt = 1; kt < 16; ++kt)
            mx = fmaxf(fmaxf(mx, s[kt][0]),
                       fmaxf(s[kt][1], fmaxf(s[kt][2], s[kt][3])));
        mx = fmaxf(mx, __shfl_xor(mx, 16));
        mx = fmaxf(mx, __shfl_xor(mx, 32));

        // p = exp(s - mx) = exp2(fma(s, log2e, -mx*log2e)) : 2 VALU/elem
        float nm = -mx * LOG2E;
        float l = 0.f;
#pragma unroll
        for (int kt = 0; kt < 16; ++kt) {
#pragma unroll
            for (int r = 0; r < 4; ++r) {
                float p = __builtin_amdgcn_exp2f(fmaf(s[kt][r], LOG2E, nm));
                s[kt][r] = p;
                l += p;
            }
        }
        l += __shfl_xor(l, 16);
        l += __shfl_xor(l, 32);
        float inv = __builtin_amdgcn_rcpf(l);   // feeds bf16, approx rcp is fine

        float4v o0 = {0.f, 0.f, 0.f, 0.f}, o1 = {0.f, 0.f, 0.f, 0.f};
#pragma unroll
        for (int P = 0; P < 8; ++P) {
            union { u32 w[4]; short8v v; } pf;
            pf.w[0] = cvt_pk_bf16(s[2 * P][0],     s[2 * P][1]);
            pf.w[1] = cvt_pk_bf16(s[2 * P][2],     s[2 * P][3]);
            pf.w[2] = cvt_pk_bf16(s[2 * P + 1][0], s[2 * P + 1][1]);
            pf.w[3] = cvt_pk_bf16(s[2 * P + 1][2], s[2 * P + 1][3]);
            short8v v0 = *(const short8v*)&Vf[(P * 2 + 0) * 512 + lane * 8];
            short8v v1 = *(const short8v*)&Vf[(P * 2 + 1) * 512 + lane * 8];
            o0 = __builtin_amdgcn_mfma_f32_16x16x32_bf16(pf.v, v0, o0, 0, 0, 0);
            o1 = __builtin_amdgcn_mfma_f32_16x16x32_bf16(pf.v, v1, o1, 0, 0, 0);
        }

        int token0 = tb * 256 + rep * 64 + wave * 16;
#pragma unroll
        for (int r = 0; r < 4; ++r) {
            float invr = __shfl(inv, quad * 4 + r);
            u16* row = att + ((size_t)(b * N_TOK + token0 + quad * 4 + r)) * C_DIM + h * HD;
            row[ln]      = f2bf_hw(o0[r] * invr);
            row[16 + ln] = f2bf_hw(o1[r] * invr);
        }
    }
}

// ---------------- Kernel D: out projection + residual via MFMA --------------
// v2: Bf from prepped fragment buffer (coalesced) when available; epilogue
// remapped to 16 lanes/row x 12 passes (256B contiguous per 16-lane group).
__global__ __launch_bounds__(256) void proj_res_mfma(
    const u16* __restrict__ att, const float* __restrict__ Wp,
    const u16* __restrict__ WpF, const float* __restrict__ bp,
    const float* __restrict__ x, float* __restrict__ y)
{
    __shared__ float Tf[C_DIM * 68];   // [c][tok] fp32 transpose, stride 68
    int b = blockIdx.x >> 8;
    int n0 = (blockIdx.x & 255) * 64;
    int t = threadIdx.x;
    int wv = t >> 6, lane = t & 63;
    int q8 = lane >> 4, ln = lane & 15;

    short8v Bf[18];
    if (WpF) {
        // coalesced 16B fragment loads, no dependency chain
#pragma unroll
        for (int i = 0; i < 18; ++i)
            Bf[i] = *(const short8v*)&WpF[(wv * 18 + i) * 512 + lane * 8];
    } else {
        // fallback: build from Wp directly (strided)
#pragma unroll
        for (int kt = 0; kt < 6; ++kt) {
#pragma unroll
            for (int jj = 0; jj < 3; ++jj) {
                const float* w0 = Wp + (kt * 32 + q8 * 8) * C_DIM + (wv * 3 + jj) * 16 + ln;
                union { u32 w[4]; short8v v; } f;
#pragma unroll
                for (int wj = 0; wj < 4; ++wj)
                    f.w[wj] = cvt_pk_bf16(w0[(2 * wj) * C_DIM], w0[(2 * wj + 1) * C_DIM]);
                Bf[kt * 3 + jj] = f.v;
            }
        }
    }

#pragma unroll
    for (int mt = 0; mt < 4; ++mt) {
        const u16* ab = att + ((size_t)(b * N_TOK + n0 + mt * 16 + ln)) * C_DIM + q8 * 8;
        float4v acc[3] = {{0.f,0.f,0.f,0.f},{0.f,0.f,0.f,0.f},{0.f,0.f,0.f,0.f}};
#pragma unroll
        for (int kt = 0; kt < 6; ++kt) {
            short8v a = *(const short8v*)(ab + kt * 32);
#pragma unroll
            for (int jj = 0; jj < 3; ++jj)
                acc[jj] = __builtin_amdgcn_mfma_f32_16x16x32_bf16(a, Bf[kt * 3 + jj], acc[jj], 0, 0, 0);
        }
#pragma unroll
        for (int jj = 0; jj < 3; ++jj)
#pragma unroll
            for (int r = 0; r < 4; ++r)
                Tf[((wv * 3 + jj) * 16 + ln) * 68 + mt * 16 + q8 * 4 + r] = acc[jj][r];
    }
    __syncthreads();

    // epilogue: 16 lanes per channel row -> 256B contiguous per 16-lane group,
    // all 256 threads active, 12 passes cover 192 channels.
    {
        int r0 = t >> 4;      // 0..15
        int p  = t & 15;      // float4 index along tokens
#pragma unroll
        for (int pass = 0; pass < 12; ++pass) {
            int c = pass * 16 + r0;
            float bias = bp[c];
            float4 a = *(const float4*)&Tf[c * 68 + p * 4];
            const float4* xr = (const float4*)(x + (((size_t)(b * C_DIM + c)) << 14) + n0);
            float4*       yr = (float4*)(y + (((size_t)(b * C_DIM + c)) << 14) + n0);
            float4 u = xr[p];
            float4 w;
            w.x = a.x + bias + u.x;
            w.y = a.y + bias + u.y;
            w.z = a.z + bias + u.z;
            w.w = a.w + bias + u.w;
            yr[p] = w;
        }
    }
}

extern "C" void kernel_launch(void* const* d_in, const int* in_sizes, int n_in,
                              void* d_out, int out_size, void* d_ws, size_t ws_size,
                              hipStream_t stream) {
    const float* x     = (const float*)d_in[0];
    const float* prior = (const float*)d_in[1];
    const float* ln1_g = (const float*)d_in[2];
    const float* ln1_b = (const float*)d_in[3];
    const float* ln2_g = (const float*)d_in[4];
    const float* ln2_b = (const float*)d_in[5];
    const float* Wq    = (const float*)d_in[6];
    const float* Wkv   = (const float*)d_in[7];
    const float* Wp    = (const float*)d_in[8];
    const float* bp    = (const float*)d_in[9];

    // d_out (50.3 MB fp32) multiplexed (y overwrites everything at the end):
    //   [0,        25165824): q bf16
    //   [25165824, 25952256): k fp32
    //   [25952256, 26738688): v fp32
    //   [26738688, 26812416): WqF  bf16 fragment-ordered (72 frags x 1KB)
    //   [26812416, 27205632): KfG  bf16 fragments (24 x 16KB)
    //   [27205632, 27598848): VfG  bf16 fragments (24 x 16KB)
    // d_ws: att bf16 (25.2 MB) + WpF (72 KB) — WpF must NOT be in d_out since
    // proj reads it while writing y over all of d_out (cross-block race).
    char* outc = (char*)d_out;
    u16*   q    = (u16*)outc;
    float* kbuf = (float*)(outc + 25165824);
    float* vbuf = (float*)(outc + 25952256);
    u16*   WqF  = (u16*)(outc + 26738688);
    u16*   KfG  = (u16*)(outc + 26812416);
    u16*   VfG  = (u16*)(outc + 27205632);
    u16*   att  = (u16*)d_ws;
    float* y    = (float*)d_out;

    bool has_wpf = ws_size >= (size_t)25165824 + 73728;
    u16* WpF = has_wpf ? (u16*)((char*)d_ws + 25165824) : (u16*)nullptr;

    wq_prep<<<18, 256, 0, stream>>>(Wq, WqF);
    if (has_wpf) wq_prep<<<18, 256, 0, stream>>>(Wp, WpF);
    ln1_q_mfma<<<1024, 256, 0, stream>>>(x, ln1_g, ln1_b, WqF, q);
    ln2_kv_kernel<<<1024, 192, 0, stream>>>(prior, ln2_g, ln2_b, Wkv, kbuf, vbuf);
    kv_prep<<<24, 256, 0, stream>>>(kbuf, vbuf, KfG, VfG);
    attn_mfma_kernel<<<1536, 256, 0, stream>>>(q, KfG, VfG, att);
    proj_res_mfma<<<1024, 256, 0, stream>>>(att, Wp, WpF, bp, x, y);
}